// Round 1
// baseline (149.084 us; speedup 1.0000x reference)
//
#include <hip/hip_runtime.h>

// PooledSSIMLoss: x,y (16,3,512,512) fp32, WINDOW=11 VALID box filters,
// SSIM map (48,502,502) -> scalar 1 - mean.

#define WIN     11
#define IMG     512
#define OUTW    502            // 512 - 11 + 1
#define SEG     32             // output rows per block
#define NSEG    16             // ceil(502/32)
#define NPLANES 48             // 16*3
#define RINGN   12             // raw-row ring depth (need rows r-11 .. r)
#define STRIDE  516            // 512 + 4 zero-pad cols

#define C1f     (0.01f * 0.01f)        // (K1*L)^2
#define C2f     (0.03f * 0.03f)        // (K2*L)^2
#define EPSf    1e-8f
#define INV121  (1.0f / 121.0f)

__global__ __launch_bounds__(128) void ssim_init(double* acc) {
    acc[0] = 0.0;
}

__global__ __launch_bounds__(128) void ssim_main(const float* __restrict__ x,
                                                 const float* __restrict__ y,
                                                 double* __restrict__ acc) {
    __shared__ float ring[2][RINGN][STRIDE];
    __shared__ float wsum[2];

    const int t     = threadIdx.x;       // 0..127
    const int plane = blockIdx.y;        // 0..47
    const int seg   = blockIdx.x;        // 0..15
    const int o0    = seg * SEG;
    const int o1    = (o0 + SEG < OUTW) ? (o0 + SEG) : OUTW;
    const int r0    = o0;                // first input row
    const int r1    = o1 + WIN - 2;      // last input row (<= 511)

    const float* xp = x + (size_t)plane * IMG * IMG;
    const float* yp = y + (size_t)plane * IMG * IMG;

    const int  c0     = 4 * t;           // first output col of this thread
    const bool active = (c0 < OUTW);

    // Vertical running box sums over rows, for 14 columns c0..c0+13.
    float Vx[14], Vy[14], Vxx[14], Vyy[14], Vxy[14];
#pragma unroll
    for (int j = 0; j < 14; ++j) { Vx[j]=0.f; Vy[j]=0.f; Vxx[j]=0.f; Vyy[j]=0.f; Vxy[j]=0.f; }

    float lsum = 0.0f;

    // Prefetch first row (1 float4 per array per thread covers 512 cols).
    float4 px = ((const float4*)(xp + (size_t)r0 * IMG))[t];
    float4 py = ((const float4*)(yp + (size_t)r0 * IMG))[t];

    int slot = 0;
    for (int r = r0; r <= r1; ++r) {
        // ---- stage current row into ring ----
        ((float4*)&ring[0][slot][0])[t] = px;
        ((float4*)&ring[1][slot][0])[t] = py;
        if (t < 4) { ring[0][slot][512 + t] = 0.0f; ring[1][slot][512 + t] = 0.0f; }
        // issue-early prefetch of next row (latency hides under compute below)
        if (r < r1) {
            px = ((const float4*)(xp + (size_t)(r + 1) * IMG))[t];
            py = ((const float4*)(yp + (size_t)(r + 1) * IMG))[t];
        }
        __syncthreads();

        if (active) {
            // ---- subtract row leaving the window ----
            if (r - r0 >= WIN) {
                int os = slot - WIN; if (os < 0) os += RINGN;
                const float4* xr = (const float4*)&ring[0][os][0];
                const float4* yr = (const float4*)&ring[1][os][0];
                float4 a0 = xr[t], a1 = xr[t+1], a2 = xr[t+2], a3 = xr[t+3];
                float4 b0 = yr[t], b1 = yr[t+1], b2 = yr[t+2], b3 = yr[t+3];
                float xn[16], yn[16];
                xn[0]=a0.x; xn[1]=a0.y; xn[2]=a0.z; xn[3]=a0.w;
                xn[4]=a1.x; xn[5]=a1.y; xn[6]=a1.z; xn[7]=a1.w;
                xn[8]=a2.x; xn[9]=a2.y; xn[10]=a2.z; xn[11]=a2.w;
                xn[12]=a3.x; xn[13]=a3.y; xn[14]=a3.z; xn[15]=a3.w;
                yn[0]=b0.x; yn[1]=b0.y; yn[2]=b0.z; yn[3]=b0.w;
                yn[4]=b1.x; yn[5]=b1.y; yn[6]=b1.z; yn[7]=b1.w;
                yn[8]=b2.x; yn[9]=b2.y; yn[10]=b2.z; yn[11]=b2.w;
                yn[12]=b3.x; yn[13]=b3.y; yn[14]=b3.z; yn[15]=b3.w;
#pragma unroll
                for (int j = 0; j < 14; ++j) {
                    float xv = xn[j], yv = yn[j];
                    Vx[j]  -= xv;      Vy[j]  -= yv;
                    Vxx[j] -= xv * xv; Vyy[j] -= yv * yv; Vxy[j] -= xv * yv;
                }
            }
            // ---- add the new row ----
            {
                const float4* xr = (const float4*)&ring[0][slot][0];
                const float4* yr = (const float4*)&ring[1][slot][0];
                float4 a0 = xr[t], a1 = xr[t+1], a2 = xr[t+2], a3 = xr[t+3];
                float4 b0 = yr[t], b1 = yr[t+1], b2 = yr[t+2], b3 = yr[t+3];
                float xn[16], yn[16];
                xn[0]=a0.x; xn[1]=a0.y; xn[2]=a0.z; xn[3]=a0.w;
                xn[4]=a1.x; xn[5]=a1.y; xn[6]=a1.z; xn[7]=a1.w;
                xn[8]=a2.x; xn[9]=a2.y; xn[10]=a2.z; xn[11]=a2.w;
                xn[12]=a3.x; xn[13]=a3.y; xn[14]=a3.z; xn[15]=a3.w;
                yn[0]=b0.x; yn[1]=b0.y; yn[2]=b0.z; yn[3]=b0.w;
                yn[4]=b1.x; yn[5]=b1.y; yn[6]=b1.z; yn[7]=b1.w;
                yn[8]=b2.x; yn[9]=b2.y; yn[10]=b2.z; yn[11]=b2.w;
                yn[12]=b3.x; yn[13]=b3.y; yn[14]=b3.z; yn[15]=b3.w;
#pragma unroll
                for (int j = 0; j < 14; ++j) {
                    float xv = xn[j], yv = yn[j];
                    Vx[j]  += xv;      Vy[j]  += yv;
                    Vxx[j] += xv * xv; Vyy[j] += yv * yv; Vxy[j] += xv * yv;
                }
            }
            // ---- emit one output row once the window is full ----
            if (r - r0 >= WIN - 1) {
                float hx = 0.f, hy = 0.f, hxx = 0.f, hyy = 0.f, hxy = 0.f;
#pragma unroll
                for (int k = 0; k < WIN; ++k) {
                    hx += Vx[k]; hy += Vy[k]; hxx += Vxx[k]; hyy += Vyy[k]; hxy += Vxy[k];
                }
#pragma unroll
                for (int j = 0; j < 4; ++j) {
                    if (j > 0) {
                        hx  += Vx[j + 10]  - Vx[j - 1];
                        hy  += Vy[j + 10]  - Vy[j - 1];
                        hxx += Vxx[j + 10] - Vxx[j - 1];
                        hyy += Vyy[j + 10] - Vyy[j - 1];
                        hxy += Vxy[j + 10] - Vxy[j - 1];
                    }
                    if (c0 + j < OUTW) {
                        float mux = hx * INV121, muy = hy * INV121;
                        float ex2 = hxx * INV121, ey2 = hyy * INV121, exy = hxy * INV121;
                        float mxs = mux * mux, mys = muy * muy, mxy = mux * muy;
                        float sx  = fmaxf(ex2 - mxs, 0.0f);
                        float sy  = fmaxf(ey2 - mys, 0.0f);
                        float sxy = exy - mxy;
                        float num = (2.0f * mxy + C1f) * (2.0f * sxy + C2f);
                        float den = (mxs + mys + C1f) * (sx + sy + C2f) + EPSf;
                        lsum += num / den;
                    }
                }
            }
        }
        __syncthreads();   // protect oldest ring slot before overwrite
        if (++slot == RINGN) slot = 0;
    }

    // ---- block reduction -> global double accumulator ----
#pragma unroll
    for (int off = 32; off > 0; off >>= 1) lsum += __shfl_down(lsum, off, 64);
    const int wid = t >> 6, lane = t & 63;
    if (lane == 0) wsum[wid] = lsum;
    __syncthreads();
    if (t == 0) atomicAdd(acc, (double)(wsum[0] + wsum[1]));
}

__global__ __launch_bounds__(128) void ssim_final(const double* __restrict__ acc,
                                                  float* __restrict__ out) {
    const double N = (double)NPLANES * OUTW * OUTW;   // 12,096,192
    out[0] = 1.0f - (float)(acc[0] / N);
}

extern "C" void kernel_launch(void* const* d_in, const int* in_sizes, int n_in,
                              void* d_out, int out_size, void* d_ws, size_t ws_size,
                              hipStream_t stream) {
    const float* x = (const float*)d_in[0];
    const float* y = (const float*)d_in[1];
    float* out = (float*)d_out;
    double* acc = (double*)d_ws;

    ssim_init<<<dim3(1), dim3(128), 0, stream>>>(acc);
    ssim_main<<<dim3(NSEG, NPLANES), dim3(128), 0, stream>>>(x, y, acc);
    ssim_final<<<dim3(1), dim3(128), 0, stream>>>(acc, out);
}

// Round 2
// 140.425 us; speedup vs baseline: 1.0617x; 1.0617x over previous
//
#include <hip/hip_runtime.h>

// PooledSSIMLoss: x,y (16,3,512,512) fp32, 11x11 VALID box filters,
// SSIM map (48,502,502) -> scalar 1 - mean.
//
// R2 structure: thread owns 4 columns (c0=4t). Vertical running sums V* for
// 5 quantities live in registers (no redundancy). Per row: write V quads to
// LDS H-buffer (double-buffered), 1 sync, horizontal 11-tap via 3 neighbor
// ds_read_b128 per quantity + own quad in regs. Old row (r-11) re-fetched
// from global (L2/L3-hot) instead of an LDS raw ring.

#define WIN     11
#define IMG     512
#define OUTW    502            // 512 - 11 + 1
#define SEG     16             // output rows per block
#define NSEG    32             // ceil(502/16)
#define NPLANES 48             // 16*3
#define NPART   (NSEG * NPLANES)   // 1536
#define HSTR    516            // 512 + 4 zero-pad cols

#define C1f     (0.01f * 0.01f)
#define C2f     (0.03f * 0.03f)
#define EPSf    1e-8f
#define INV121  (1.0f / 121.0f)

__global__ __launch_bounds__(64) void ssim_zero(double* acc) {
    if (threadIdx.x == 0) acc[0] = 0.0;
}

// mode 0: part[bid] = block sum (no init needed). mode 1: atomicAdd(part, sum).
__global__ __launch_bounds__(128) void ssim_main(const float* __restrict__ x,
                                                 const float* __restrict__ y,
                                                 double* __restrict__ part,
                                                 int mode) {
    __shared__ float H[2][5][HSTR];
    __shared__ float wsum[2];

    const int t     = threadIdx.x;       // 0..127
    const int plane = blockIdx.y;        // 0..47
    const int seg   = blockIdx.x;        // 0..31
    const int o0    = seg * SEG;
    const int o1    = (o0 + SEG < OUTW) ? (o0 + SEG) : OUTW;
    const int r0    = o0;
    const int r1    = o1 + WIN - 2;      // <= 511

    const float4* xp4 = (const float4*)(x + (size_t)plane * IMG * IMG);
    const float4* yp4 = (const float4*)(y + (size_t)plane * IMG * IMG);

    const int  c0     = 4 * t;
    const bool active = (c0 < OUTW);     // t <= 125

    // zero the 4 pad columns of every H row (visible after first sync)
    if (t < 4) {
#pragma unroll
        for (int b = 0; b < 2; ++b)
#pragma unroll
            for (int q = 0; q < 5; ++q)
                H[b][q][512 + t] = 0.0f;
    }

    float Vx[4]  = {0.f, 0.f, 0.f, 0.f};
    float Vy[4]  = {0.f, 0.f, 0.f, 0.f};
    float Vxx[4] = {0.f, 0.f, 0.f, 0.f};
    float Vyy[4] = {0.f, 0.f, 0.f, 0.f};
    float Vxy[4] = {0.f, 0.f, 0.f, 0.f};

    float4 nx = xp4[r0 * 128 + t];
    float4 ny = yp4[r0 * 128 + t];
    float4 ox = make_float4(0.f, 0.f, 0.f, 0.f);
    float4 oy = make_float4(0.f, 0.f, 0.f, 0.f);

    float lsum = 0.0f;
    int buf = 0;

    for (int r = r0; r <= r1; ++r) {
        // ---- prefetch next iteration's rows (issue early, use late) ----
        float4 nx2 = nx, ny2 = ny, ox2 = ox, oy2 = oy;
        if (r < r1) {
            nx2 = xp4[(r + 1) * 128 + t];
            ny2 = yp4[(r + 1) * 128 + t];
            if (r - r0 >= WIN - 1) {               // next iter subtracts row r+1-11
                ox2 = xp4[(r + 1 - WIN) * 128 + t];
                oy2 = yp4[(r + 1 - WIN) * 128 + t];
            }
        }

        // ---- vertical running sums: subtract leaving row, add new row ----
        if (r - r0 >= WIN) {
            const float xo[4] = {ox.x, ox.y, ox.z, ox.w};
            const float yo[4] = {oy.x, oy.y, oy.z, oy.w};
#pragma unroll
            for (int j = 0; j < 4; ++j) {
                Vx[j] -= xo[j];
                Vy[j] -= yo[j];
                Vxx[j] = fmaf(-xo[j], xo[j], Vxx[j]);
                Vyy[j] = fmaf(-yo[j], yo[j], Vyy[j]);
                Vxy[j] = fmaf(-xo[j], yo[j], Vxy[j]);
            }
        }
        {
            const float xn[4] = {nx.x, nx.y, nx.z, nx.w};
            const float yn[4] = {ny.x, ny.y, ny.z, ny.w};
#pragma unroll
            for (int j = 0; j < 4; ++j) {
                Vx[j] += xn[j];
                Vy[j] += yn[j];
                Vxx[j] = fmaf(xn[j], xn[j], Vxx[j]);
                Vyy[j] = fmaf(yn[j], yn[j], Vyy[j]);
                Vxy[j] = fmaf(xn[j], yn[j], Vxy[j]);
            }
        }

        // ---- publish V quads for the horizontal pass ----
        ((float4*)&H[buf][0][0])[t] = make_float4(Vx[0],  Vx[1],  Vx[2],  Vx[3]);
        ((float4*)&H[buf][1][0])[t] = make_float4(Vy[0],  Vy[1],  Vy[2],  Vy[3]);
        ((float4*)&H[buf][2][0])[t] = make_float4(Vxx[0], Vxx[1], Vxx[2], Vxx[3]);
        ((float4*)&H[buf][3][0])[t] = make_float4(Vyy[0], Vyy[1], Vyy[2], Vyy[3]);
        ((float4*)&H[buf][4][0])[t] = make_float4(Vxy[0], Vxy[1], Vxy[2], Vxy[3]);
        __syncthreads();

        // ---- horizontal 11-tap + SSIM for output row r-10 ----
        if (active && r - r0 >= WIN - 1) {
            float hx[4], hy[4], hxx[4], hyy[4], hxy[4];
#define HORIZ(V, q, h)                                                        \
            {                                                                 \
                const float4* rp = (const float4*)&H[buf][q][0];              \
                float4 n1 = rp[t + 1], n2 = rp[t + 2], n3 = rp[t + 3];        \
                h[0] = ((V[0] + V[1]) + (V[2] + V[3]))                        \
                     + ((n1.x + n1.y) + (n1.z + n1.w))                        \
                     + ((n2.x + n2.y) + n2.z);                                \
                h[1] = h[0] - V[0] + n2.w;                                    \
                h[2] = h[1] - V[1] + n3.x;                                    \
                h[3] = h[2] - V[2] + n3.y;                                    \
            }
            HORIZ(Vx,  0, hx)
            HORIZ(Vy,  1, hy)
            HORIZ(Vxx, 2, hxx)
            HORIZ(Vyy, 3, hyy)
            HORIZ(Vxy, 4, hxy)
#undef HORIZ
#pragma unroll
            for (int j = 0; j < 4; ++j) {
                if (c0 + j < OUTW) {
                    float mux = hx[j]  * INV121, muy = hy[j]  * INV121;
                    float ex2 = hxx[j] * INV121, ey2 = hyy[j] * INV121;
                    float exy = hxy[j] * INV121;
                    float mxs = mux * mux, mys = muy * muy, mxy = mux * muy;
                    float sx  = fmaxf(fmaf(-mux, mux, ex2), 0.0f);
                    float sy  = fmaxf(fmaf(-muy, muy, ey2), 0.0f);
                    float sxy = exy - mxy;
                    float num = fmaf(2.0f, mxy, C1f) * fmaf(2.0f, sxy, C2f);
                    float den = fmaf(mxs + mys + C1f, sx + sy + C2f, EPSf);
                    float rr  = __builtin_amdgcn_rcpf(den);
                    rr = rr * (2.0f - den * rr);          // 1 Newton step
                    lsum = fmaf(num, rr, lsum);
                }
            }
        }

        buf ^= 1;
        nx = nx2; ny = ny2; ox = ox2; oy = oy2;
    }

    // ---- block reduction ----
#pragma unroll
    for (int off = 32; off > 0; off >>= 1) lsum += __shfl_down(lsum, off, 64);
    const int wid = t >> 6, lane = t & 63;
    if (lane == 0) wsum[wid] = lsum;
    __syncthreads();
    if (t == 0) {
        double bs = (double)(wsum[0] + wsum[1]);
        if (mode == 0) part[blockIdx.y * NSEG + blockIdx.x] = bs;
        else           atomicAdd(part, bs);
    }
}

__global__ __launch_bounds__(256) void ssim_final(const double* __restrict__ part,
                                                  int n, float* __restrict__ out) {
    __shared__ double s[4];
    double v = 0.0;
    for (int i = threadIdx.x; i < n; i += 256) v += part[i];
#pragma unroll
    for (int off = 32; off > 0; off >>= 1) v += __shfl_down(v, off, 64);
    if ((threadIdx.x & 63) == 0) s[threadIdx.x >> 6] = v;
    __syncthreads();
    if (threadIdx.x == 0) {
        double tot = s[0] + s[1] + s[2] + s[3];
        const double N = (double)NPLANES * OUTW * OUTW;   // 12,096,192
        out[0] = 1.0f - (float)(tot / N);
    }
}

extern "C" void kernel_launch(void* const* d_in, const int* in_sizes, int n_in,
                              void* d_out, int out_size, void* d_ws, size_t ws_size,
                              hipStream_t stream) {
    const float* x = (const float*)d_in[0];
    const float* y = (const float*)d_in[1];
    float* out = (float*)d_out;
    double* part = (double*)d_ws;

    if (ws_size >= (size_t)NPART * sizeof(double)) {
        // 2-kernel path: per-block partials, no init kernel needed.
        ssim_main<<<dim3(NSEG, NPLANES), dim3(128), 0, stream>>>(x, y, part, 0);
        ssim_final<<<dim3(1), dim3(256), 0, stream>>>(part, NPART, out);
    } else {
        // fallback: single-double accumulator via atomics.
        ssim_zero<<<dim3(1), dim3(64), 0, stream>>>(part);
        ssim_main<<<dim3(NSEG, NPLANES), dim3(128), 0, stream>>>(x, y, part, 1);
        ssim_final<<<dim3(1), dim3(256), 0, stream>>>(part, 1, out);
    }
}